// Round 6
// baseline (168.083 us; speedup 1.0000x reference)
//
#include <hip/hip_runtime.h>
#include <stdint.h>

// BacklashNet: per-row nonlinear scan (backlash/hysteresis), fully fused,
// single-buffer LDS, async global->LDS staging, occupancy-first.
//
// R1 (70 us): fused single pass, 32KB buf, 4 blk/CU but TWO block
//   generations, phase-aligned bursts.
// R2 (97 us): register prefetch spilled (VGPR capped 128). Reverted.
// R3 (42.8 us): global_load_lds + 64KB double-buffer + counted vmcnt; but
//   __syncthreads drains vmcnt(0) -> prefetch dead. 2 blk/CU only.
// R4 (42.8 us, NULL): asm barriers with "memory" clobber -> legalizer
//   inserted the full drain anyway. Counters bit-identical to R3.
// R5 (99.9 us, REGRESSION): clobber-free waits + sched_barrier(0) pins
//   emitted but defeated the compiler scheduler (guide m141). Reverted.
//
// Conclusion from R3/R4/R5: intra-block pipelining is not the lever; the
// kernel is LATENCY-bound at 4 waves/CU (1 wave/SIMD) — drains, LDS and
// HBM latency all unhidden.
// R6: occupancy-first. Single 32 KB buffer (~33.8 KB LDS) -> 4 blocks/CU,
//   8 waves/CU (2/SIMD). Grid 1024 x 2 rows (one generation). Plain
//   __syncthreads everywhere; its vmcnt drain is hidden by CROSS-BLOCK
//   overlap (other blocks on the CU compute while this one drains).
//
// Verified machinery byte-identical (passed, absmax 7.8e-3):
//   - linear-dest global_load_lds with SOURCE-side XOR swizzle:
//       slot s <- x4[(s>>4)*16 + ((s&15) ^ ((s>>4)&15))]
//   - read-side swizzle slot(c,f)=c*16+(f^(c&15)): 0 bank conflicts
//   - bit-exact bstep (__f*_rn, reference op order)
//   - acceptance: chunk c+1 valid iff e0[c]==e1[c] bitwise; all-converged
//     => pass B outputs exact; failure -> uniform cooperative stitch.

namespace {

constexpr int kB  = 2048;
constexpr int kT  = 8192;
constexpr int kNC = 128;           // chunks per row == threads per block
constexpr int kRPB = 2;            // rows per block
constexpr int kGrid = kB / kRPB;   // 1024 blocks -> 4/CU, one generation

__device__ __forceinline__ float bstep(float xv, float prev, float m_lo, float m_up,
                                       float mlc, float muc) {
  float A1 = __fmul_rn(m_lo, xv);
  float B1 = __fadd_rn(A1, mlc);
  float A2 = __fmul_rn(m_up, xv);
  float B2 = __fadd_rn(A2, muc);
  float C  = __fadd_rn(__fadd_rn(B1, A2), muc);
  float u  = __fsub_rn(prev, A2);
  bool  f1 = (B1 <= prev);
  bool  f2 = (u <= muc);
  float hi = f2 ? C  : B1;
  float lo = f2 ? B2 : prev;
  return f1 ? hi : lo;
}

// Async-stage one row: 16 x global_load_lds(16B) per thread, linear LDS
// dest (slot s = j*128 + tid), pre-swizzled global source.
__device__ __forceinline__ void issue_row(const float* __restrict__ xrow,
                                          float4* __restrict__ buf, int tid) {
#pragma unroll
  for (int j = 0; j < 16; ++j) {
    const int s  = j * 128 + tid;
    const int cc = s >> 4, fs = s & 15;
    const int g  = cc * 16 + (fs ^ (cc & 15));
    __builtin_amdgcn_global_load_lds(
        (const __attribute__((address_space(1))) uint32_t*)(xrow + 4 * (size_t)g),
        (__attribute__((address_space(3))) uint32_t*)(buf + s),
        16, 0, 0);
  }
}

// Process one fully-staged row out of sb. If !kLast, ends with a barrier
// so the caller may immediately re-stage sb.
template <bool kLast>
__device__ __forceinline__ void process_row(
    float4* __restrict__ sb, float* __restrict__ se0, float* __restrict__ se1,
    int* __restrict__ sflag, float* __restrict__ sfix,
    float* __restrict__ out, int r, int c, float p0r,
    float m_lo, float m_up, float mlc, float muc) {
  // my chunk -> registers (conflict-free swizzled b128 column reads)
  float4 xb[16];
#pragma unroll
  for (int f = 0; f < 16; ++f) xb[f] = sb[c * 16 + (f ^ (c & 15))];

  // pass A: exit from guess entry
  float pa = (c == 0) ? p0r : 0.0f;
#pragma unroll
  for (int q = 0; q < 16; ++q) {
    pa = bstep(xb[q].x, pa, m_lo, m_up, mlc, muc);
    pa = bstep(xb[q].y, pa, m_lo, m_up, mlc, muc);
    pa = bstep(xb[q].z, pa, m_lo, m_up, mlc, muc);
    pa = bstep(xb[q].w, pa, m_lo, m_up, mlc, muc);
  }
  se0[c] = pa;
  __syncthreads();

  // pass B: run from e0[c-1], write outputs in-place over x in LDS
  float pb = (c == 0) ? p0r : se0[c - 1];
#pragma unroll
  for (int q = 0; q < 16; ++q) {
    float o0 = bstep(xb[q].x, pb, m_lo, m_up, mlc, muc);
    float o1 = bstep(xb[q].y, o0, m_lo, m_up, mlc, muc);
    float o2 = bstep(xb[q].z, o1, m_lo, m_up, mlc, muc);
    float o3 = bstep(xb[q].w, o2, m_lo, m_up, mlc, muc);
    sb[c * 16 + (q ^ (c & 15))] = make_float4(o0, o1, o2, o3);
    pb = o3;
  }
  se1[c] = pb;

  // acceptance: chunk c+1 valid iff e0[c]==e1[c] bitwise
  const bool conv = (c == kNC - 1) || (pa == pb);
  const unsigned long long bal = __ballot(conv);
  if ((c & 63) == 0) sflag[c >> 6] = (bal == ~0ull);
  __syncthreads();  // publishes se1, sb outputs, flags

  if (!(sflag[0] && sflag[1])) {
    // Rare exact stitch (uniform branches; decisions from LDS broadcasts).
    float t = se1[0];
    for (int cc = 1; cc < kNC; ++cc) {
      const bool valid = (se0[cc - 1] == t);
      if (valid) {
        t = se1[cc];
      } else {
        __syncthreads();
        if (c == cc) {
          float pf = t;
#pragma unroll
          for (int q = 0; q < 16; ++q) {
            float o0 = bstep(xb[q].x, pf, m_lo, m_up, mlc, muc);
            float o1 = bstep(xb[q].y, o0, m_lo, m_up, mlc, muc);
            float o2 = bstep(xb[q].z, o1, m_lo, m_up, mlc, muc);
            float o3 = bstep(xb[q].w, o2, m_lo, m_up, mlc, muc);
            sb[c * 16 + (q ^ (c & 15))] = make_float4(o0, o1, o2, o3);
            pf = o3;
          }
          *sfix = pf;
        }
        __syncthreads();
        t = *sfix;
      }
    }
    __syncthreads();  // publish rewritten columns
  }

  // coalesced flush: LDS -> out (inverse transpose), 1 KB/instr/wave
  float4* o4 = reinterpret_cast<float4*>(out + (size_t)r * kT);
#pragma unroll
  for (int j = 0; j < 16; ++j) {
    const int g  = j * 128 + c;
    const int cc = g >> 4, f = g & 15;
    o4[g] = sb[cc * 16 + (f ^ (cc & 15))];
  }
  if (!kLast) {
    __syncthreads();  // all waves' sb reads done -> safe to re-stage
  }
}

__global__ __launch_bounds__(128, 2) void backlash_fused(
    const float* __restrict__ x, const float* __restrict__ p0,
    const float* __restrict__ w, float* __restrict__ out) {
  __shared__ float4 sb[kNC * 16];        // single 32 KB buffer
  __shared__ float  se0[kNC], se1[kNC];
  __shared__ int    sflag[2];
  __shared__ float  sfix;

  const int c  = threadIdx.x;
  const int r0 = blockIdx.x * kRPB;
  const float m_lo = w[0], m_up = w[1];
  const float mlc = __fmul_rn(m_lo, w[2]), muc = __fmul_rn(m_up, w[3]);

  // row 0
  issue_row(x + (size_t)r0 * kT, sb, c);
  __syncthreads();  // drain: loads landed on all waves
  process_row<false>(sb, se0, se1, sflag, &sfix, out, r0, c, p0[r0],
                     m_lo, m_up, mlc, muc);

  // row 1
  issue_row(x + (size_t)(r0 + 1) * kT, sb, c);
  __syncthreads();
  process_row<true>(sb, se0, se1, sflag, &sfix, out, r0 + 1, c, p0[r0 + 1],
                    m_lo, m_up, mlc, muc);
}

}  // namespace

extern "C" void kernel_launch(void* const* d_in, const int* in_sizes, int n_in,
                              void* d_out, int out_size, void* d_ws, size_t ws_size,
                              hipStream_t stream) {
  const float* x  = (const float*)d_in[0];   // (B, T, 1) fp32
  const float* p0 = (const float*)d_in[1];   // (B, 1, 1) fp32
  const float* w  = (const float*)d_in[2];   // (4,) fp32
  float* out = (float*)d_out;                // (B, T, 1) fp32
  (void)in_sizes; (void)n_in; (void)out_size; (void)d_ws; (void)ws_size;

  backlash_fused<<<kGrid, kNC, 0, stream>>>(x, p0, w, out);
}

// Round 7
// 132.559 us; speedup vs baseline: 1.2680x; 1.2680x over previous
//
#include <hip/hip_runtime.h>
#include <stdint.h>

// BacklashNet: per-row nonlinear scan (backlash/hysteresis), fully fused,
// single-buffer LDS, async global->LDS staging, occupancy-first, NO
// register x-cache (spill-proof).
//
// R1 (70 us): fused, 32KB buf, but VGPR=128 + xb cache -> hidden spill
//   (WRITE was 109 MB, not 64); two block generations, phase-aligned.
// R2 (97 us): explicit register prefetch spilled. Reverted.
// R3 (42.8 us): 64KB double-buffer, 2 blk/CU, VGPR 180 no spill; counted
//   vmcnt dead (syncthreads drains). Best so far.
// R4 (42.8 us, NULL): "memory"-clobber asm barriers -> legalizer re-
//   inserted full drains. Counters bit-identical.
// R5 (99.9 us): sched_barrier(0) pins defeated the scheduler (m141).
// R6 (82.5 us): single 32KB buf, 4 blk/CU... compiler capped VGPR at 128
//   and SPILLED xb[16]: WRITE 64->129.5 MB, FETCH 33->67.8 MB. Occupancy
//   doubled but scratch round-trips ate it.
// R7: R6 minus the register cache. Both passes read x straight from LDS
//   (same verified conflict-free swizzled float4 pattern, issued in-loop).
//   Live set ~50 VGPR -> no spill at the 128 cap; 4 blk/CU stands.
//   Stitch replay (never fires on this data; correctness path) re-reads
//   its chunk from global, since pass B overwrote sb.
//
// Verified machinery byte-identical (passed, absmax 7.8e-3):
//   - linear-dest global_load_lds with SOURCE-side XOR swizzle:
//       slot s <- x4[(s>>4)*16 + ((s&15) ^ ((s>>4)&15))]
//   - read-side swizzle slot(c,f)=c*16+(f^(c&15)): 0 bank conflicts
//   - bit-exact bstep (__f*_rn, reference op order)
//   - acceptance: chunk c+1 valid iff e0[c]==e1[c] bitwise; all-converged
//     => pass B outputs exact; failure -> uniform cooperative stitch.

namespace {

constexpr int kB  = 2048;
constexpr int kT  = 8192;
constexpr int kNC = 128;           // chunks per row == threads per block
constexpr int kRPB = 2;            // rows per block
constexpr int kGrid = kB / kRPB;   // 1024 blocks -> 4/CU, one generation

__device__ __forceinline__ float bstep(float xv, float prev, float m_lo, float m_up,
                                       float mlc, float muc) {
  float A1 = __fmul_rn(m_lo, xv);
  float B1 = __fadd_rn(A1, mlc);
  float A2 = __fmul_rn(m_up, xv);
  float B2 = __fadd_rn(A2, muc);
  float C  = __fadd_rn(__fadd_rn(B1, A2), muc);
  float u  = __fsub_rn(prev, A2);
  bool  f1 = (B1 <= prev);
  bool  f2 = (u <= muc);
  float hi = f2 ? C  : B1;
  float lo = f2 ? B2 : prev;
  return f1 ? hi : lo;
}

// Async-stage one row: 16 x global_load_lds(16B) per thread, linear LDS
// dest (slot s = j*128 + tid), pre-swizzled global source.
__device__ __forceinline__ void issue_row(const float* __restrict__ xrow,
                                          float4* __restrict__ buf, int tid) {
#pragma unroll
  for (int j = 0; j < 16; ++j) {
    const int s  = j * 128 + tid;
    const int cc = s >> 4, fs = s & 15;
    const int g  = cc * 16 + (fs ^ (cc & 15));
    __builtin_amdgcn_global_load_lds(
        (const __attribute__((address_space(1))) uint32_t*)(xrow + 4 * (size_t)g),
        (__attribute__((address_space(3))) uint32_t*)(buf + s),
        16, 0, 0);
  }
}

// Process one fully-staged row out of sb. If !kLast, ends with a barrier
// so the caller may immediately re-stage sb.
template <bool kLast>
__device__ __forceinline__ void process_row(
    const float* __restrict__ x,
    float4* __restrict__ sb, float* __restrict__ se0, float* __restrict__ se1,
    int* __restrict__ sflag, float* __restrict__ sfix,
    float* __restrict__ out, int r, int c, float p0r,
    float m_lo, float m_up, float mlc, float muc) {
  // pass A: exit from guess entry; x read from LDS in-loop (no reg cache)
  float pa = (c == 0) ? p0r : 0.0f;
#pragma unroll
  for (int q = 0; q < 16; ++q) {
    const float4 xv = sb[c * 16 + (q ^ (c & 15))];
    pa = bstep(xv.x, pa, m_lo, m_up, mlc, muc);
    pa = bstep(xv.y, pa, m_lo, m_up, mlc, muc);
    pa = bstep(xv.z, pa, m_lo, m_up, mlc, muc);
    pa = bstep(xv.w, pa, m_lo, m_up, mlc, muc);
  }
  se0[c] = pa;
  __syncthreads();

  // pass B: run from e0[c-1]; read x slot, overwrite same slot with output
  float pb = (c == 0) ? p0r : se0[c - 1];
#pragma unroll
  for (int q = 0; q < 16; ++q) {
    const int slot = c * 16 + (q ^ (c & 15));
    const float4 xv = sb[slot];
    float o0 = bstep(xv.x, pb, m_lo, m_up, mlc, muc);
    float o1 = bstep(xv.y, o0, m_lo, m_up, mlc, muc);
    float o2 = bstep(xv.z, o1, m_lo, m_up, mlc, muc);
    float o3 = bstep(xv.w, o2, m_lo, m_up, mlc, muc);
    sb[slot] = make_float4(o0, o1, o2, o3);
    pb = o3;
  }
  se1[c] = pb;

  // acceptance: chunk c+1 valid iff e0[c]==e1[c] bitwise
  const bool conv = (c == kNC - 1) || (pa == pb);
  const unsigned long long bal = __ballot(conv);
  if ((c & 63) == 0) sflag[c >> 6] = (bal == ~0ull);
  __syncthreads();  // publishes se1, sb outputs, flags

  if (!(sflag[0] && sflag[1])) {
    // Rare exact stitch (uniform branches; decisions from LDS broadcasts).
    // sb now holds outputs, so the owner replays from GLOBAL x (slow path,
    // correctness only — never taken on this data distribution).
    float t = se1[0];
    for (int cc = 1; cc < kNC; ++cc) {
      const bool valid = (se0[cc - 1] == t);
      if (valid) {
        t = se1[cc];
      } else {
        __syncthreads();
        if (c == cc) {
          const float4* xg =
              reinterpret_cast<const float4*>(x + (size_t)r * kT + cc * 64);
          float pf = t;
#pragma unroll
          for (int q = 0; q < 16; ++q) {
            const float4 xv = xg[q];
            float o0 = bstep(xv.x, pf, m_lo, m_up, mlc, muc);
            float o1 = bstep(xv.y, o0, m_lo, m_up, mlc, muc);
            float o2 = bstep(xv.z, o1, m_lo, m_up, mlc, muc);
            float o3 = bstep(xv.w, o2, m_lo, m_up, mlc, muc);
            sb[c * 16 + (q ^ (c & 15))] = make_float4(o0, o1, o2, o3);
            pf = o3;
          }
          *sfix = pf;
        }
        __syncthreads();
        t = *sfix;
      }
    }
    __syncthreads();  // publish rewritten columns
  }

  // coalesced flush: LDS -> out (inverse transpose), 1 KB/instr/wave
  float4* o4 = reinterpret_cast<float4*>(out + (size_t)r * kT);
#pragma unroll
  for (int j = 0; j < 16; ++j) {
    const int g  = j * 128 + c;
    const int cc = g >> 4, f = g & 15;
    o4[g] = sb[cc * 16 + (f ^ (cc & 15))];
  }
  if (!kLast) {
    __syncthreads();  // all waves' sb reads done -> safe to re-stage
  }
}

__global__ __launch_bounds__(128, 2) void backlash_fused(
    const float* __restrict__ x, const float* __restrict__ p0,
    const float* __restrict__ w, float* __restrict__ out) {
  __shared__ float4 sb[kNC * 16];        // single 32 KB buffer
  __shared__ float  se0[kNC], se1[kNC];
  __shared__ int    sflag[2];
  __shared__ float  sfix;

  const int c  = threadIdx.x;
  const int r0 = blockIdx.x * kRPB;
  const float m_lo = w[0], m_up = w[1];
  const float mlc = __fmul_rn(m_lo, w[2]), muc = __fmul_rn(m_up, w[3]);

  // row 0
  issue_row(x + (size_t)r0 * kT, sb, c);
  __syncthreads();  // drain: loads landed on all waves
  process_row<false>(x, sb, se0, se1, sflag, &sfix, out, r0, c, p0[r0],
                     m_lo, m_up, mlc, muc);

  // row 1
  issue_row(x + (size_t)(r0 + 1) * kT, sb, c);
  __syncthreads();
  process_row<true>(x, sb, se0, se1, sflag, &sfix, out, r0 + 1, c, p0[r0 + 1],
                    m_lo, m_up, mlc, muc);
}

}  // namespace

extern "C" void kernel_launch(void* const* d_in, const int* in_sizes, int n_in,
                              void* d_out, int out_size, void* d_ws, size_t ws_size,
                              hipStream_t stream) {
  const float* x  = (const float*)d_in[0];   // (B, T, 1) fp32
  const float* p0 = (const float*)d_in[1];   // (B, 1, 1) fp32
  const float* w  = (const float*)d_in[2];   // (4,) fp32
  float* out = (float*)d_out;                // (B, T, 1) fp32
  (void)in_sizes; (void)n_in; (void)out_size; (void)d_ws; (void)ws_size;

  backlash_fused<<<kGrid, kNC, 0, stream>>>(x, p0, w, out);
}

// Round 8
// 115.466 us; speedup vs baseline: 1.4557x; 1.1480x over previous
//
#include <hip/hip_runtime.h>
#include <stdint.h>

// BacklashNet: per-row nonlinear scan (backlash/hysteresis).
// WAVE-PER-ROW, ZERO-BARRIER streaming design.
//
// History:
//  R1 70us fused block/row; R2 97us reg-prefetch spill; R3 42.8us dbuf+
//  global_load_lds (syncthreads drains vmcnt -> prefetch dead); R4 42.8us
//  NULL ("memory"-clobber asm re-drained); R5 99.9us sched_barrier pins
//  defeated scheduler; R6 82.5us 4blk/CU but VGPR-128 spill; R7 46us
//  spill fixed, occupancy up, STILL ~2.2 TB/s.
//  Diagnosis: all barrier-phased variants converge to ~2.2-2.5 TB/s. The
//  blocks on a CU are phase-ALIGNED (equal-duration barrier-paced phases)
//  -> stage bursts align, compute phases leave memory idle; duty ~35%.
//
// R8: remove phase-locking entirely.
//  - 1 wave (64 lanes) per row, grid 2048. NO s_barrier anywhere; waves
//    drift freely, memory stays fed.
//  - row = 4 segments x 2048 elems. chunk = lane: 64 chunks x 32 steps.
//  - staging: coalesced float4 loads -> named ping-pong reg buffers A/B
//    (static indexing; VGPR cap 256 at launch_bounds(64,2) -> no spill)
//    -> ds_write into 8KB wave-private swizzled transpose buffer.
//    Only vmcnt wait = compiler-auto at next segment's ds_write, issued
//    one full segment (~2000cy) earlier. No inline asm at all.
//  - cross-chunk comms (exits/acceptance/carried state) via __shfl /
//    __ballot, not LDS.
//  - LDS swizzle slot(c,f)=c*8+(f^(c&7)): all phases spread 64 lanes
//    uniformly over the 8 four-bank groups -> conflict-free b128.
//  - acceptance per segment (exact, bitwise): chunk 0 runs from TRUE
//    carried t; conv[c] = (pa[c]==pb[c]); all-conv => pass-B outputs are
//    the exact serial outputs and t' = pb[63]. Rare failure -> in-wave
//    stitch (uniform branches, owner replays from GLOBAL x since LDS now
//    holds outputs).
//  - bstep bit-exact (__f*_rn, reference op order) — unchanged since R0.

namespace {

constexpr int kT    = 8192;
constexpr int kSeg  = 2048;          // elements per segment
constexpr int kF4   = kSeg / 4;      // 512 float4 slots (8 KB)
constexpr int kNSeg = kT / kSeg;     // 4 segments per row

__device__ __forceinline__ float bstep(float xv, float prev, float m_lo, float m_up,
                                       float mlc, float muc) {
  float A1 = __fmul_rn(m_lo, xv);
  float B1 = __fadd_rn(A1, mlc);
  float A2 = __fmul_rn(m_up, xv);
  float B2 = __fadd_rn(A2, muc);
  float C  = __fadd_rn(__fadd_rn(B1, A2), muc);
  float u  = __fsub_rn(prev, A2);
  bool  f1 = (B1 <= prev);
  bool  f2 = (u <= muc);
  float hi = f2 ? C  : B1;
  float lo = f2 ? B2 : prev;
  return f1 ? hi : lo;
}

// Coalesced fetch of one segment into a register buffer (8 x 1KB/wave).
__device__ __forceinline__ void seg_fetch(const float4* __restrict__ xr, int seg,
                                          int l, float4 (&buf)[8]) {
#pragma unroll
  for (int j = 0; j < 8; ++j) buf[j] = xr[seg * kF4 + j * 64 + l];
}

// Stage registers -> swizzled LDS transpose. Global float4 g=(j*64+l):
// chunk c=g>>3, frag f=g&7, slot = c*8 + (f^(c&7)).
// Bank group of slot = slot&7 = (l&7)^((l>>3)&7): uniform over 64 lanes.
__device__ __forceinline__ void seg_stage(float4* __restrict__ sb, int l,
                                          const float4 (&buf)[8]) {
#pragma unroll
  for (int j = 0; j < 8; ++j) {
    const int g = j * 64 + l, c = g >> 3, f = g & 7;
    sb[c * 8 + (f ^ (c & 7))] = buf[j];
  }
}

// Process one staged segment; returns the new carried row state.
__device__ __forceinline__ float process_seg(
    float4* __restrict__ sb, const float* __restrict__ x,
    float4* __restrict__ o4, int r, int seg, int l, float t,
    float m_lo, float m_up, float mlc, float muc) {
  // pass A: from guess (true t for chunk 0, else 0)
  float pa = (l == 0) ? t : 0.0f;
#pragma unroll
  for (int f = 0; f < 8; ++f) {
    const float4 xv = sb[l * 8 + (f ^ (l & 7))];
    pa = bstep(xv.x, pa, m_lo, m_up, mlc, muc);
    pa = bstep(xv.y, pa, m_lo, m_up, mlc, muc);
    pa = bstep(xv.z, pa, m_lo, m_up, mlc, muc);
    pa = bstep(xv.w, pa, m_lo, m_up, mlc, muc);
  }

  // pass B: from neighbor's pass-A exit (true t for chunk 0); outputs
  // overwrite the x slots in LDS.
  float ent = __shfl_up(pa, 1);
  if (l == 0) ent = t;
  float pb = ent;
#pragma unroll
  for (int f = 0; f < 8; ++f) {
    const int slot = l * 8 + (f ^ (l & 7));
    const float4 xv = sb[slot];
    float o0 = bstep(xv.x, pb, m_lo, m_up, mlc, muc);
    float o1 = bstep(xv.y, o0, m_lo, m_up, mlc, muc);
    float o2 = bstep(xv.z, o1, m_lo, m_up, mlc, muc);
    float o3 = bstep(xv.w, o2, m_lo, m_up, mlc, muc);
    sb[slot] = make_float4(o0, o1, o2, o3);
    pb = o3;
  }

  // acceptance: chunk c+1's pass-B entry (=pa[c]) is true iff pa[c]==pb[c]
  const bool conv = (pa == pb) || (l == 63);
  if (__ballot(conv) == ~0ull) {
    t = __shfl(pb, 63);             // all exact: carried state = pb[63]
  } else {
    // Rare exact stitch, fully in-wave (uniform branches via shfl
    // broadcasts). LDS holds outputs, so replay reads global x.
    float tc = __shfl(pb, 0);       // chunk 0 ran from true t
    for (int cc = 1; cc < 64; ++cc) {
      const float used = __shfl(pa, cc - 1);   // pass-B entry of chunk cc
      if (used == tc) {
        tc = __shfl(pb, cc);
      } else {
        float pf = tc;
        if (l == cc) {
          const float4* xg = reinterpret_cast<const float4*>(
              x + (size_t)r * kT + seg * kSeg + cc * 32);
#pragma unroll
          for (int f = 0; f < 8; ++f) {
            const float4 xv = xg[f];
            float o0 = bstep(xv.x, pf, m_lo, m_up, mlc, muc);
            float o1 = bstep(xv.y, o0, m_lo, m_up, mlc, muc);
            float o2 = bstep(xv.z, o1, m_lo, m_up, mlc, muc);
            float o3 = bstep(xv.w, o2, m_lo, m_up, mlc, muc);
            sb[l * 8 + (f ^ (l & 7))] = make_float4(o0, o1, o2, o3);
            pf = o3;
          }
        }
        tc = __shfl(pf, cc);
      }
    }
    t = tc;
  }

  // coalesced flush: LDS -> out, 8 x 1KB/wave store instructions
#pragma unroll
  for (int j = 0; j < 8; ++j) {
    const int g = j * 64 + l, c = g >> 3, f = g & 7;
    o4[seg * kF4 + g] = sb[c * 8 + (f ^ (c & 7))];
  }
  return t;
}

__global__ __launch_bounds__(64, 2) void backlash_wave(
    const float* __restrict__ x, const float* __restrict__ p0,
    const float* __restrict__ w, float* __restrict__ out) {
  __shared__ float4 sb[kF4];           // 8 KB wave-private transpose buffer

  const int l = threadIdx.x;
  const int r = blockIdx.x;
  const float m_lo = w[0], m_up = w[1];
  const float mlc = __fmul_rn(m_lo, w[2]), muc = __fmul_rn(m_up, w[3]);
  const float4* xr = reinterpret_cast<const float4*>(x + (size_t)r * kT);
  float4* o4 = reinterpret_cast<float4*>(out + (size_t)r * kT);

  float t = p0[r];
  float4 A[8], B[8];

  // ping-pong register double-buffer, fully static (4 segments unrolled)
  seg_fetch(xr, 0, l, A);
  seg_stage(sb, l, A);                 // vmcnt auto-wait for A here
  seg_fetch(xr, 1, l, B);              // in flight across seg 0 compute
  t = process_seg(sb, x, o4, r, 0, l, t, m_lo, m_up, mlc, muc);

  seg_stage(sb, l, B);                 // waits B (issued 1 segment ago)
  seg_fetch(xr, 2, l, A);
  t = process_seg(sb, x, o4, r, 1, l, t, m_lo, m_up, mlc, muc);

  seg_stage(sb, l, A);
  seg_fetch(xr, 3, l, B);
  t = process_seg(sb, x, o4, r, 2, l, t, m_lo, m_up, mlc, muc);

  seg_stage(sb, l, B);
  t = process_seg(sb, x, o4, r, 3, l, t, m_lo, m_up, mlc, muc);
}

}  // namespace

extern "C" void kernel_launch(void* const* d_in, const int* in_sizes, int n_in,
                              void* d_out, int out_size, void* d_ws, size_t ws_size,
                              hipStream_t stream) {
  const float* x  = (const float*)d_in[0];   // (B, T, 1) fp32
  const float* p0 = (const float*)d_in[1];   // (B, 1, 1) fp32
  const float* w  = (const float*)d_in[2];   // (4,) fp32
  float* out = (float*)d_out;                // (B, T, 1) fp32
  (void)in_sizes; (void)n_in; (void)out_size; (void)d_ws; (void)ws_size;

  backlash_wave<<<2048, 64, 0, stream>>>(x, p0, w, out);
}